// Round 1
// baseline (3562.860 us; speedup 1.0000x reference)
//
#include <hip/hip_runtime.h>

// GCN 2-layer forward: out = GCN2(relu(GCN1(x)))
// GCNConv: out = D^{-1/2} (A + I) D^{-1/2} X W + b, deg = in-degree(dst)+1.
//
// Baseline strategy (round 1): atomic scatter-add aggregation.
//   deg/dinv once (shared by both layers), dense GEMMs for X@W,
//   self-loop folded into the aggregation-init pass, bias folded where legal.

#define F_IN 64
#define HDIM 128
#define CDIM 32

__global__ void k_init_deg(float* __restrict__ deg, int n) {
    int i = blockIdx.x * blockDim.x + threadIdx.x;
    if (i < n) deg[i] = 1.0f;  // self loop
}

__global__ void k_count_deg(const int* __restrict__ dst, int e, float* __restrict__ deg) {
    int i = blockIdx.x * blockDim.x + threadIdx.x;
    if (i < e) atomicAdd(&deg[dst[i]], 1.0f);
}

__global__ void k_dinv(float* __restrict__ deg, int n) {
    int i = blockIdx.x * blockDim.x + threadIdx.x;
    if (i < n) deg[i] = rsqrtf(deg[i]);  // deg >= 1 always
}

// h1[row][col] = sum_k x[row][k] * W1[k][col];  one block (128 thr) per row
__global__ void k_gemm1(const float* __restrict__ x, const float* __restrict__ W,
                        float* __restrict__ h, int n) {
    __shared__ float xs[F_IN];
    int row = blockIdx.x;
    if (row >= n) return;
    int col = threadIdx.x;  // 0..127
    if (col < F_IN) xs[col] = x[row * F_IN + col];
    __syncthreads();
    float acc = 0.f;
#pragma unroll
    for (int k = 0; k < F_IN; ++k) acc = fmaf(xs[k], W[k * HDIM + col], acc);
    h[row * HDIM + col] = acc;
}

// agg[v][:] = dinv[v]^2 * h1[v][:]   (self-loop contribution), float4 over n*32
__global__ void k_agg_init1(const float* __restrict__ h1, const float* __restrict__ dinv,
                            float* __restrict__ agg, int n) {
    int i = blockIdx.x * blockDim.x + threadIdx.x;
    if (i >= n * (HDIM / 4)) return;
    int v = i / (HDIM / 4);
    float s = dinv[v];
    s = s * s;
    float4 val = ((const float4*)h1)[i];
    val.x *= s; val.y *= s; val.z *= s; val.w *= s;
    ((float4*)agg)[i] = val;
}

// per edge: agg[dst][:] += dinv[src]*dinv[dst] * h1[src][:]; 32 thr/edge, float4 each
__global__ void k_scatter1(const int* __restrict__ src, const int* __restrict__ dst,
                           const float* __restrict__ dinv, const float* __restrict__ h1,
                           float* __restrict__ agg, int e) {
    int gid = blockIdx.x * blockDim.x + threadIdx.x;
    int edge = gid >> 5;
    if (edge >= e) return;
    int lane = gid & 31;
    int s = src[edge], d = dst[edge];
    float norm = dinv[s] * dinv[d];
    float4 v = ((const float4*)(h1 + (size_t)s * HDIM))[lane];
    float* o = agg + (size_t)d * HDIM + lane * 4;
    atomicAdd(o + 0, v.x * norm);
    atomicAdd(o + 1, v.y * norm);
    atomicAdd(o + 2, v.z * norm);
    atomicAdd(o + 3, v.w * norm);
}

__global__ void k_relu_bias(float* __restrict__ hbuf, const float* __restrict__ b, int n) {
    int i = blockIdx.x * blockDim.x + threadIdx.x;
    if (i >= n * HDIM) return;
    int f = i & (HDIM - 1);
    float v = hbuf[i] + b[f];
    hbuf[i] = v > 0.f ? v : 0.f;
}

// h2 = h @ W2 : [n,128]x[128,32]; block = 256 thr = 8 rows x 32 cols
__global__ void k_gemm2(const float* __restrict__ hbuf, const float* __restrict__ W,
                        float* __restrict__ h2, int n) {
    __shared__ float hs[8][HDIM];
    int r0 = blockIdx.x * 8;
    int tid = threadIdx.x;
    // cooperative load of 8 rows (1024 floats) via 256 float4s
    {
        int rows_avail = n - r0;
        if (rows_avail >= 8) {
            ((float4*)hs)[tid] = ((const float4*)(hbuf + (size_t)r0 * HDIM))[tid];
        } else {
            // tail-safe path
            for (int j = tid; j < rows_avail * HDIM; j += blockDim.x)
                ((float*)hs)[j] = hbuf[(size_t)r0 * HDIM + j];
        }
    }
    __syncthreads();
    int r = tid >> 5, c = tid & 31;
    if (r0 + r >= n) return;
    float acc = 0.f;
#pragma unroll
    for (int k = 0; k < HDIM; ++k) acc = fmaf(hs[r][k], W[k * CDIM + c], acc);
    h2[(size_t)(r0 + r) * CDIM + c] = acc;
}

// out[v][c] = dinv[v]^2 * h2[v][c] + b2[c]   (self-loop + bias)
__global__ void k_agg_init2(const float* __restrict__ h2, const float* __restrict__ dinv,
                            const float* __restrict__ b2, float* __restrict__ out, int n) {
    int i = blockIdx.x * blockDim.x + threadIdx.x;
    if (i >= n * CDIM) return;
    int v = i >> 5;
    int c = i & 31;
    float s = dinv[v];
    out[i] = s * s * h2[i] + b2[c];
}

// per edge: out[dst][:] += norm * h2[src][:]; 8 thr/edge, float4 each
__global__ void k_scatter2(const int* __restrict__ src, const int* __restrict__ dst,
                           const float* __restrict__ dinv, const float* __restrict__ h2,
                           float* __restrict__ out, int e) {
    int gid = blockIdx.x * blockDim.x + threadIdx.x;
    int edge = gid >> 3;
    if (edge >= e) return;
    int lane = gid & 7;
    int s = src[edge], d = dst[edge];
    float norm = dinv[s] * dinv[d];
    float4 v = ((const float4*)(h2 + (size_t)s * CDIM))[lane];
    float* o = out + (size_t)d * CDIM + lane * 4;
    atomicAdd(o + 0, v.x * norm);
    atomicAdd(o + 1, v.y * norm);
    atomicAdd(o + 2, v.z * norm);
    atomicAdd(o + 3, v.w * norm);
}

extern "C" void kernel_launch(void* const* d_in, const int* in_sizes, int n_in,
                              void* d_out, int out_size, void* d_ws, size_t ws_size,
                              hipStream_t stream) {
    const float* x   = (const float*)d_in[0];
    const int*   ei  = (const int*)d_in[1];
    const float* W1  = (const float*)d_in[2];
    const float* b1  = (const float*)d_in[3];
    const float* W2  = (const float*)d_in[4];
    const float* b2  = (const float*)d_in[5];
    float* out = (float*)d_out;

    int n = in_sizes[0] / F_IN;
    int e = in_sizes[1] / 2;
    const int* srcIdx = ei;       // edge_index[0]
    const int* dstIdx = ei + e;   // edge_index[1]

    // workspace layout (floats): dinv[n] | h1[n*128] | hbuf[n*128]; h2 reuses h1
    float* dinv = (float*)d_ws;
    float* h1   = dinv + n;
    float* hbuf = h1 + (size_t)n * HDIM;
    float* h2   = h1;  // h1 dead after scatter1+relu

    const int B = 256;

    // degree + dinv (shared by both layers)
    k_init_deg<<<(n + B - 1) / B, B, 0, stream>>>(dinv, n);
    k_count_deg<<<(e + B - 1) / B, B, 0, stream>>>(dstIdx, e, dinv);
    k_dinv<<<(n + B - 1) / B, B, 0, stream>>>(dinv, n);

    // layer 1
    k_gemm1<<<n, 128, 0, stream>>>(x, W1, h1, n);
    k_agg_init1<<<(n * (HDIM / 4) + B - 1) / B, B, 0, stream>>>(h1, dinv, hbuf, n);
    {
        long long tot = (long long)e * 32;
        k_scatter1<<<(int)((tot + B - 1) / B), B, 0, stream>>>(srcIdx, dstIdx, dinv, h1, hbuf, e);
    }
    k_relu_bias<<<(n * HDIM + B - 1) / B, B, 0, stream>>>(hbuf, b1, n);

    // layer 2
    k_gemm2<<<(n + 7) / 8, 256, 0, stream>>>(hbuf, W2, h2, n);
    k_agg_init2<<<(n * CDIM + B - 1) / B, B, 0, stream>>>(h2, dinv, b2, out, n);
    {
        long long tot = (long long)e * 8;
        k_scatter2<<<(int)((tot + B - 1) / B), B, 0, stream>>>(srcIdx, dstIdx, dinv, h2, out, e);
    }
}

// Round 2
// 614.257 us; speedup vs baseline: 5.8003x; 5.8003x over previous
//
#include <hip/hip_runtime.h>

// GCN 2-layer forward, round 2: CSR-by-dst + atomic-free gather aggregation.
// Layer 1 aggregates BEFORE the GEMM (F=64 < H=128 halves gather traffic):
//   ax[v]  = dinv[v]*sum_{s in N(v)} dinv[s]*x[s] + dinv[v]^2 * x[v]
//   h[v]   = relu(ax[v] @ W1 + b1)
// Layer 2 transforms first (C=32 < H=128):
//   h2 = h @ W2
//   out[v] = dinv[v]*sum dinv[s]*h2[s] + dinv[v]^2*h2[v] + b2

#define F_IN 64
#define HDIM 128
#define CDIM 32
#define SCAN_B 256

// ---------- CSR build ----------
__global__ void k_zero(int* __restrict__ p, int n) {
    int i = blockIdx.x * blockDim.x + threadIdx.x;
    if (i < n) p[i] = 0;
}

__global__ void k_hist(const int* __restrict__ dst, int e, int* __restrict__ cnt) {
    int i = blockIdx.x * blockDim.x + threadIdx.x;
    if (i < e) atomicAdd(&cnt[dst[i]], 1);
}

// per-block exclusive scan; bsum[b] = block total
__global__ void k_scan_block(const int* __restrict__ cnt, int* __restrict__ rowptr,
                             int* __restrict__ bsum, int n) {
    __shared__ int sh[SCAN_B];
    int tid = threadIdx.x;
    int i = blockIdx.x * SCAN_B + tid;
    int v = (i < n) ? cnt[i] : 0;
    sh[tid] = v;
    __syncthreads();
    for (int off = 1; off < SCAN_B; off <<= 1) {
        int t = (tid >= off) ? sh[tid - off] : 0;
        __syncthreads();
        sh[tid] += t;
        __syncthreads();
    }
    if (i < n) rowptr[i] = sh[tid] - v;            // exclusive
    if (tid == SCAN_B - 1) bsum[blockIdx.x] = sh[tid];
}

__global__ void k_scan_bsums(int* __restrict__ bsum, int nb) {
    if (threadIdx.x == 0 && blockIdx.x == 0) {
        int run = 0;
        for (int i = 0; i < nb; ++i) { int t = bsum[i]; bsum[i] = run; run += t; }
    }
}

// rowptr += block offset; cursor = rowptr; dinv = rsqrt(deg+1)
__global__ void k_scan_add_prep(int* __restrict__ rowptr, const int* __restrict__ bsum,
                                const int* __restrict__ cnt, int* __restrict__ cursor,
                                float* __restrict__ dinv, int n) {
    int i = blockIdx.x * blockDim.x + threadIdx.x;
    if (i >= n) return;
    int rp = rowptr[i] + bsum[i / SCAN_B];
    rowptr[i] = rp;
    cursor[i] = rp;
    dinv[i] = rsqrtf((float)(cnt[i] + 1));
}

__global__ void k_fill(const int* __restrict__ src, const int* __restrict__ dst, int e,
                       int* __restrict__ cursor, int* __restrict__ col) {
    int i = blockIdx.x * blockDim.x + threadIdx.x;
    if (i >= e) return;
    int pos = atomicAdd(&cursor[dst[i]], 1);
    col[pos] = src[i];
}

// ---------- layer 1 ----------
// one wave (64 lanes) per node, lane = feature; 4 nodes per 256-block
__global__ void k_gather1(const float* __restrict__ x, const int* __restrict__ rowptr,
                          const int* __restrict__ cnt, const int* __restrict__ col,
                          const float* __restrict__ dinv, float* __restrict__ ax, int n) {
    int v = blockIdx.x * 4 + (threadIdx.x >> 6);
    if (v >= n) return;
    int lane = threadIdx.x & 63;
    int beg = rowptr[v], deg = cnt[v];
    float dv = dinv[v];
    float acc = 0.f;
    for (int j = 0; j < deg; ++j) {
        int s = col[beg + j];
        acc = fmaf(dinv[s], x[(size_t)s * F_IN + lane], acc);
    }
    ax[(size_t)v * F_IN + lane] = dv * acc + dv * dv * x[(size_t)v * F_IN + lane];
}

// h = relu(ax @ W1 + b1): 256 thr = 2 rows x 128 cols
__global__ void k_gemm1(const float* __restrict__ ax, const float* __restrict__ W,
                        const float* __restrict__ b, float* __restrict__ h, int n) {
    __shared__ float xs[2][F_IN];
    int r0 = blockIdx.x * 2;
    int tid = threadIdx.x;
    if (tid < 2 * F_IN) {
        int rr = tid >> 6, cc = tid & 63;
        if (r0 + rr < n) xs[rr][cc] = ax[(size_t)(r0 + rr) * F_IN + cc];
    }
    __syncthreads();
    int r = tid >> 7, c = tid & 127;
    if (r0 + r >= n) return;
    float acc = 0.f;
#pragma unroll
    for (int k = 0; k < F_IN; ++k) acc = fmaf(xs[r][k], W[k * HDIM + c], acc);
    acc += b[c];
    h[(size_t)(r0 + r) * HDIM + c] = acc > 0.f ? acc : 0.f;
}

// ---------- layer 2 ----------
// h2 = h @ W2 : 256 thr = 8 rows x 32 cols
__global__ void k_gemm2(const float* __restrict__ h, const float* __restrict__ W,
                        float* __restrict__ h2, int n) {
    __shared__ float hs[8][HDIM];
    int r0 = blockIdx.x * 8;
    int tid = threadIdx.x;
    int rows_avail = n - r0;
    if (rows_avail >= 8) {
        ((float4*)hs)[tid] = ((const float4*)(h + (size_t)r0 * HDIM))[tid];
    } else {
        for (int j = tid; j < rows_avail * HDIM; j += blockDim.x)
            ((float*)hs)[j] = h[(size_t)r0 * HDIM + j];
    }
    __syncthreads();
    int r = tid >> 5, c = tid & 31;
    if (r0 + r >= n) return;
    float acc = 0.f;
#pragma unroll
    for (int k = 0; k < HDIM; ++k) acc = fmaf(hs[r][k], W[k * CDIM + c], acc);
    h2[(size_t)(r0 + r) * CDIM + c] = acc;
}

// 32 lanes per node, 8 nodes per 256-block
__global__ void k_gather2(const float* __restrict__ h2, const int* __restrict__ rowptr,
                          const int* __restrict__ cnt, const int* __restrict__ col,
                          const float* __restrict__ dinv, const float* __restrict__ b2,
                          float* __restrict__ out, int n) {
    int v = blockIdx.x * 8 + (threadIdx.x >> 5);
    if (v >= n) return;
    int lane = threadIdx.x & 31;
    int beg = rowptr[v], deg = cnt[v];
    float dv = dinv[v];
    float acc = 0.f;
    for (int j = 0; j < deg; ++j) {
        int s = col[beg + j];
        acc = fmaf(dinv[s], h2[(size_t)s * CDIM + lane], acc);
    }
    out[(size_t)v * CDIM + lane] = dv * acc + dv * dv * h2[(size_t)v * CDIM + lane] + b2[lane];
}

extern "C" void kernel_launch(void* const* d_in, const int* in_sizes, int n_in,
                              void* d_out, int out_size, void* d_ws, size_t ws_size,
                              hipStream_t stream) {
    const float* x  = (const float*)d_in[0];
    const int*   ei = (const int*)d_in[1];
    const float* W1 = (const float*)d_in[2];
    const float* b1 = (const float*)d_in[3];
    const float* W2 = (const float*)d_in[4];
    const float* b2 = (const float*)d_in[5];
    float* out = (float*)d_out;

    int n = in_sizes[0] / F_IN;
    int e = in_sizes[1] / 2;
    const int* srcIdx = ei;
    const int* dstIdx = ei + e;

    int nb = (n + SCAN_B - 1) / SCAN_B;

    // workspace layout
    int* cnt    = (int*)d_ws;            // n
    int* rowptr = cnt + n;               // n
    int* cursor = rowptr + n;            // n
    int* bsum   = cursor + n;            // nb (pad to 4096)
    int* col    = bsum + 4096;           // e
    float* dinv = (float*)(col + e);     // n
    float* ax   = dinv + n;              // n*64
    float* h    = ax + (size_t)n * F_IN; // n*128
    float* h2   = h + (size_t)n * HDIM;  // n*32

    const int B = 256;

    // CSR build + dinv
    k_zero<<<(n + B - 1) / B, B, 0, stream>>>(cnt, n);
    k_hist<<<(e + B - 1) / B, B, 0, stream>>>(dstIdx, e, cnt);
    k_scan_block<<<nb, SCAN_B, 0, stream>>>(cnt, rowptr, bsum, n);
    k_scan_bsums<<<1, 64, 0, stream>>>(bsum, nb);
    k_scan_add_prep<<<(n + B - 1) / B, B, 0, stream>>>(rowptr, bsum, cnt, cursor, dinv, n);
    k_fill<<<(e + B - 1) / B, B, 0, stream>>>(srcIdx, dstIdx, e, cursor, col);

    // layer 1: aggregate (F=64) then GEMM+bias+relu
    k_gather1<<<(n + 3) / 4, B, 0, stream>>>(x, rowptr, cnt, col, dinv, ax, n);
    k_gemm1<<<(n + 1) / 2, B, 0, stream>>>(ax, W1, b1, h, n);

    // layer 2: GEMM then aggregate (C=32) + bias
    k_gemm2<<<(n + 7) / 8, B, 0, stream>>>(h, W2, h2, n);
    k_gather2<<<(n + 7) / 8, B, 0, stream>>>(h2, rowptr, cnt, col, dinv, b2, out, n);
}

// Round 3
// 417.018 us; speedup vs baseline: 8.5437x; 1.4730x over previous
//
#include <hip/hip_runtime.h>

// GCN 2-layer forward, round 3:
//   CSR-by-dst + atomic-free gathers, dinv prescaled at producers,
//   edge loops unrolled x4 for memory-level parallelism,
//   layer1 fully fused: gather(xs) -> relu(@W1+b1) -> @W2 -> h2s (prescaled).
//   out[v] = dinv[v]*(sum_{s in N(v)} h2s[s] + h2s[v]) + b2
// where xs = dinv .* x, h2s = dinv .* (relu(agg1@W1+b1) @ W2).

#define F_IN 64
#define HDIM 128
#define CDIM 32
#define SCAN_B 256

// ---------- CSR build ----------
__global__ void k_zero(int* __restrict__ p, int n) {
    int i = blockIdx.x * blockDim.x + threadIdx.x;
    if (i < n) p[i] = 0;
}

__global__ void k_hist(const int* __restrict__ dst, int e, int* __restrict__ cnt) {
    int i = blockIdx.x * blockDim.x + threadIdx.x;
    if (i < e) atomicAdd(&cnt[dst[i]], 1);
}

__global__ void k_scan_block(const int* __restrict__ cnt, int* __restrict__ rowptr,
                             int* __restrict__ bsum, int n) {
    __shared__ int sh[SCAN_B];
    int tid = threadIdx.x;
    int i = blockIdx.x * SCAN_B + tid;
    int v = (i < n) ? cnt[i] : 0;
    sh[tid] = v;
    __syncthreads();
    for (int off = 1; off < SCAN_B; off <<= 1) {
        int t = (tid >= off) ? sh[tid - off] : 0;
        __syncthreads();
        sh[tid] += t;
        __syncthreads();
    }
    if (i < n) rowptr[i] = sh[tid] - v;  // exclusive
    if (tid == SCAN_B - 1) bsum[blockIdx.x] = sh[tid];
}

// exclusive scan of block sums (nb <= 512 fast path; serial fallback otherwise)
__global__ void k_scan_bsums(int* __restrict__ bsum, int nb) {
    __shared__ int sh[512];
    int tid = threadIdx.x;
    if (nb <= 512) {
        int v = (tid < nb) ? bsum[tid] : 0;
        sh[tid] = v;
        __syncthreads();
        for (int off = 1; off < 512; off <<= 1) {
            int t = (tid >= off) ? sh[tid - off] : 0;
            __syncthreads();
            sh[tid] += t;
            __syncthreads();
        }
        if (tid < nb) bsum[tid] = sh[tid] - v;
    } else if (tid == 0) {
        int run = 0;
        for (int i = 0; i < nb; ++i) { int t = bsum[i]; bsum[i] = run; run += t; }
    }
}

// rowptr += block offset; cursor = rowptr; dinv = rsqrt(deg+1)
__global__ void k_scan_add_prep(int* __restrict__ rowptr, const int* __restrict__ bsum,
                                const int* __restrict__ cnt, int* __restrict__ cursor,
                                float* __restrict__ dinv, int n) {
    int i = blockIdx.x * blockDim.x + threadIdx.x;
    if (i >= n) return;
    int rp = rowptr[i] + bsum[i / SCAN_B];
    rowptr[i] = rp;
    cursor[i] = rp;
    dinv[i] = rsqrtf((float)(cnt[i] + 1));
}

__global__ void k_fill(const int* __restrict__ src, const int* __restrict__ dst, int e,
                       int* __restrict__ cursor, int* __restrict__ col) {
    int i = blockIdx.x * blockDim.x + threadIdx.x;
    if (i >= e) return;
    int pos = atomicAdd(&cursor[dst[i]], 1);
    col[pos] = src[i];
}

// xs = dinv .* x  (float4 over n*16)
__global__ void k_prescale(const float* __restrict__ x, const float* __restrict__ dinv,
                           float* __restrict__ xs, int n) {
    int i = blockIdx.x * blockDim.x + threadIdx.x;
    if (i >= n * (F_IN / 4)) return;
    int v = i >> 4;
    float s = dinv[v];
    float4 val = ((const float4*)x)[i];
    val.x *= s; val.y *= s; val.z *= s; val.w *= s;
    ((float4*)xs)[i] = val;
}

// ---------- fused layer 1 + transform 2 ----------
// block = 256 threads = 4 nodes x 64 lanes(=features)
// phase 1: gather ax (unroll x4), phase 2: h=relu(ax@W1+b1), phase 3: h2s=dinv*(h@W2)
__global__ void k_layer1_fused(const float* __restrict__ xs, const int* __restrict__ rowptr,
                               const int* __restrict__ cnt, const int* __restrict__ col,
                               const float* __restrict__ dinv, const float* __restrict__ W1,
                               const float* __restrict__ b1, const float* __restrict__ W2,
                               float* __restrict__ h2s, int n) {
    __shared__ float axs[4][F_IN];
    __shared__ float hs[4][HDIM];
    int tid = threadIdx.x;
    int w = tid >> 6, lane = tid & 63;
    int v = blockIdx.x * 4 + w;

    float axv = 0.f;
    if (v < n) {
        int beg = rowptr[v], deg = cnt[v];
        float a0 = 0.f, a1 = 0.f, a2 = 0.f, a3 = 0.f;
        int j = 0;
        for (; j + 4 <= deg; j += 4) {
            int s0 = col[beg + j];
            int s1 = col[beg + j + 1];
            int s2 = col[beg + j + 2];
            int s3 = col[beg + j + 3];
            a0 += xs[(size_t)s0 * F_IN + lane];
            a1 += xs[(size_t)s1 * F_IN + lane];
            a2 += xs[(size_t)s2 * F_IN + lane];
            a3 += xs[(size_t)s3 * F_IN + lane];
        }
        for (; j < deg; ++j) a0 += xs[(size_t)col[beg + j] * F_IN + lane];
        float dv = dinv[v];
        axv = dv * (((a0 + a1) + (a2 + a3)) + xs[(size_t)v * F_IN + lane]);
    }
    axs[w][lane] = axv;   // zero for out-of-range rows
    __syncthreads();

    // phase 2: each thread computes h[w][lane] and h[w][lane+64]
    float acc_a = b1[lane], acc_b = b1[lane + 64];
#pragma unroll
    for (int k = 0; k < F_IN; ++k) {
        float a = axs[w][k];                    // LDS broadcast
        acc_a = fmaf(a, W1[k * HDIM + lane], acc_a);
        acc_b = fmaf(a, W1[k * HDIM + lane + 64], acc_b);
    }
    hs[w][lane]      = acc_a > 0.f ? acc_a : 0.f;
    hs[w][lane + 64] = acc_b > 0.f ? acc_b : 0.f;
    __syncthreads();

    // phase 3: 128 threads compute h2s[r][c] = dinv * sum_k hs[r][k]*W2[k][c]
    if (tid < 4 * CDIM) {
        int r = tid >> 5, c = tid & 31;
        int vv = blockIdx.x * 4 + r;
        if (vv < n) {
            float acc = 0.f;
#pragma unroll
            for (int k = 0; k < HDIM; ++k) acc = fmaf(hs[r][k], W2[k * CDIM + c], acc);
            h2s[(size_t)vv * CDIM + c] = dinv[vv] * acc;
        }
    }
}

// ---------- layer 2 aggregation ----------
// 32 lanes per node, 8 nodes per 256-block, edge loop unrolled x4
__global__ void k_gather2(const float* __restrict__ h2s, const int* __restrict__ rowptr,
                          const int* __restrict__ cnt, const int* __restrict__ col,
                          const float* __restrict__ dinv, const float* __restrict__ b2,
                          float* __restrict__ out, int n) {
    int v = blockIdx.x * 8 + (threadIdx.x >> 5);
    if (v >= n) return;
    int lane = threadIdx.x & 31;
    int beg = rowptr[v], deg = cnt[v];
    float a0 = 0.f, a1 = 0.f, a2 = 0.f, a3 = 0.f;
    int j = 0;
    for (; j + 4 <= deg; j += 4) {
        int s0 = col[beg + j];
        int s1 = col[beg + j + 1];
        int s2 = col[beg + j + 2];
        int s3 = col[beg + j + 3];
        a0 += h2s[(size_t)s0 * CDIM + lane];
        a1 += h2s[(size_t)s1 * CDIM + lane];
        a2 += h2s[(size_t)s2 * CDIM + lane];
        a3 += h2s[(size_t)s3 * CDIM + lane];
    }
    for (; j < deg; ++j) a0 += h2s[(size_t)col[beg + j] * CDIM + lane];
    float sum = ((a0 + a1) + (a2 + a3)) + h2s[(size_t)v * CDIM + lane];
    out[(size_t)v * CDIM + lane] = dinv[v] * sum + b2[lane];
}

extern "C" void kernel_launch(void* const* d_in, const int* in_sizes, int n_in,
                              void* d_out, int out_size, void* d_ws, size_t ws_size,
                              hipStream_t stream) {
    const float* x  = (const float*)d_in[0];
    const int*   ei = (const int*)d_in[1];
    const float* W1 = (const float*)d_in[2];
    const float* b1 = (const float*)d_in[3];
    const float* W2 = (const float*)d_in[4];
    const float* b2 = (const float*)d_in[5];
    float* out = (float*)d_out;

    int n = in_sizes[0] / F_IN;
    int e = in_sizes[1] / 2;
    const int* srcIdx = ei;
    const int* dstIdx = ei + e;

    int nb = (n + SCAN_B - 1) / SCAN_B;

    // workspace layout
    int* cnt    = (int*)d_ws;             // n
    int* rowptr = cnt + n;                // n
    int* cursor = rowptr + n;             // n
    int* bsum   = cursor + n;             // nb (padded 4096)
    int* col    = bsum + 4096;            // e
    float* dinv = (float*)(col + e);      // n
    float* xs   = dinv + n;               // n*64
    float* h2s  = xs + (size_t)n * F_IN;  // n*32

    const int B = 256;

    // CSR build + dinv + prescale
    k_zero<<<(n + B - 1) / B, B, 0, stream>>>(cnt, n);
    k_hist<<<(e + B - 1) / B, B, 0, stream>>>(dstIdx, e, cnt);
    k_scan_block<<<nb, SCAN_B, 0, stream>>>(cnt, rowptr, bsum, n);
    k_scan_bsums<<<1, 512, 0, stream>>>(bsum, nb);
    k_scan_add_prep<<<(n + B - 1) / B, B, 0, stream>>>(rowptr, bsum, cnt, cursor, dinv, n);
    k_prescale<<<(n * (F_IN / 4) + B - 1) / B, B, 0, stream>>>(x, dinv, xs, n);
    k_fill<<<(e + B - 1) / B, B, 0, stream>>>(srcIdx, dstIdx, e, cursor, col);

    // fused layer 1 (+ layer-2 transform)
    k_layer1_fused<<<(n + 3) / 4, B, 0, stream>>>(xs, rowptr, cnt, col, dinv, W1, b1, W2, h2s, n);

    // layer 2 aggregation
    k_gather2<<<(n + 7) / 8, B, 0, stream>>>(h2s, rowptr, cnt, col, dinv, b2, out, n);
}